// Round 1
// baseline (4526.175 us; speedup 1.0000x reference)
//
#include <hip/hip_runtime.h>

// Problem constants (from setup_inputs: B=8, C=3, H=W=1024, all float32)
constexpr int B_ = 8;
constexpr int C_ = 3;
constexpr int H_ = 1024;
constexpr int W_ = 1024;
constexpr int HW_ = H_ * W_;

// ---------------------------------------------------------------------------
// Kernel 1: forward bilinear splat with atomics.
// img    [B,3,H,W], flow [B,2,H,W], metric [B,1,H,W]
// out    [B,3,H,W]  accumulates img*exp(metric)*w
// norm   [B,H,W]    accumulates exp(metric)*w
// ---------------------------------------------------------------------------
__global__ __launch_bounds__(256) void splat_kernel(
    const float* __restrict__ img,
    const float* __restrict__ flow,
    const float* __restrict__ metric,
    float* __restrict__ out,
    float* __restrict__ norm)
{
    const int t = blockIdx.x * blockDim.x + threadIdx.x;
    if (t >= B_ * HW_) return;

    const int b = t >> 20;          // / HW_
    const int p = t & (HW_ - 1);    // % HW_
    const int y = p >> 10;          // / W_
    const int x = p & (W_ - 1);     // % W_

    const float fx = flow[(size_t)(b * 2 + 0) * HW_ + p] + (float)x;
    const float fy = flow[(size_t)(b * 2 + 1) * HW_ + p] + (float)y;
    const float wgt = __expf(metric[(size_t)b * HW_ + p]);

    const float v0 = img[(size_t)(b * 3 + 0) * HW_ + p] * wgt;
    const float v1 = img[(size_t)(b * 3 + 1) * HW_ + p] * wgt;
    const float v2 = img[(size_t)(b * 3 + 2) * HW_ + p] * wgt;

    const float x0f = floorf(fx);
    const float y0f = floorf(fy);
    const int x0 = (int)x0f;
    const int y0 = (int)y0f;
    const float wx1 = fx - x0f;      // weight for x0+1
    const float wx0 = 1.0f - wx1;    // weight for x0
    const float wy1 = fy - y0f;
    const float wy0 = 1.0f - wy1;

    float* const outb = out + (size_t)b * 3 * HW_;
    float* const normb = norm + (size_t)b * HW_;

#pragma unroll
    for (int dy = 0; dy < 2; ++dy) {
        const int yi = y0 + dy;
        if (yi < 0 || yi >= H_) continue;
        const float wy = dy ? wy1 : wy0;
#pragma unroll
        for (int dx = 0; dx < 2; ++dx) {
            const int xi = x0 + dx;
            if (xi < 0 || xi >= W_) continue;
            const float w = (dx ? wx1 : wx0) * wy;
            const int q = yi * W_ + xi;
            // Hardware fp32 atomic add (global_atomic_add_f32); device scope.
            unsafeAtomicAdd(outb + q,            v0 * w);
            unsafeAtomicAdd(outb + HW_ + q,      v1 * w);
            unsafeAtomicAdd(outb + 2 * HW_ + q,  v2 * w);
            unsafeAtomicAdd(normb + q,           wgt * w);
        }
    }
}

// ---------------------------------------------------------------------------
// Kernel 2: out /= (norm == 0 ? 1 : norm), float4-vectorized.
// ---------------------------------------------------------------------------
__global__ __launch_bounds__(256) void normalize_kernel(
    float* __restrict__ out,
    const float* __restrict__ norm)
{
    const int t = blockIdx.x * blockDim.x + threadIdx.x;
    constexpr int Q = HW_ / 4;           // float4s per plane
    if (t >= B_ * Q) return;

    const int b = t / Q;
    const int p4 = t - b * Q;

    const float4 n4 = reinterpret_cast<const float4*>(norm + (size_t)b * HW_)[p4];
    const float ix = (n4.x == 0.0f) ? 1.0f : 1.0f / n4.x;
    const float iy = (n4.y == 0.0f) ? 1.0f : 1.0f / n4.y;
    const float iz = (n4.z == 0.0f) ? 1.0f : 1.0f / n4.z;
    const float iw = (n4.w == 0.0f) ? 1.0f : 1.0f / n4.w;

#pragma unroll
    for (int c = 0; c < 3; ++c) {
        float4* plane = reinterpret_cast<float4*>(out + (size_t)(b * 3 + c) * HW_);
        float4 v = plane[p4];
        v.x *= ix; v.y *= iy; v.z *= iz; v.w *= iw;
        plane[p4] = v;
    }
}

extern "C" void kernel_launch(void* const* d_in, const int* in_sizes, int n_in,
                              void* d_out, int out_size, void* d_ws, size_t ws_size,
                              hipStream_t stream)
{
    const float* img    = (const float*)d_in[0];
    const float* flow   = (const float*)d_in[1];
    const float* metric = (const float*)d_in[2];
    float* out  = (float*)d_out;
    float* norm = (float*)d_ws;   // B*HW floats = 32 MB

    // Zero accumulators every call (harness poisons once, never re-poisons).
    hipMemsetAsync(out,  0, (size_t)B_ * 3 * HW_ * sizeof(float), stream);
    hipMemsetAsync(norm, 0, (size_t)B_ * HW_ * sizeof(float), stream);

    {
        const int n = B_ * HW_;
        const int threads = 256;
        const int blocks = (n + threads - 1) / threads;
        splat_kernel<<<blocks, threads, 0, stream>>>(img, flow, metric, out, norm);
    }
    {
        const int n = B_ * (HW_ / 4);
        const int threads = 256;
        const int blocks = (n + threads - 1) / threads;
        normalize_kernel<<<blocks, threads, 0, stream>>>(out, norm);
    }
}